// Round 2
// baseline (53.601 us; speedup 1.0000x reference)
//
#include <hip/hip_runtime.h>

// ---------------------------------------------------------------------------
// Depthwise 1-D full correlation, per (batch, filter):
//   out[t] = sum_s y[s] * w[2047 + s - t],   t, s in [0, 4096)
// Block-Toeplitz bf16 MFMA (16x16x32), fp32 accumulate.
// Kernel 1: one block per (b,f); writes block-private (b,f,t) slab in ws.
// Kernel 2: 32x32 LDS transpose ws(b,f,t) -> out(b,t,f); every 128-B output
//           line has exactly ONE writer block (avoids cross-XCD false sharing).
// ---------------------------------------------------------------------------

#define T_LEN   4096
#define F_CH    32

// LDS layout (ushort units)
#define YP      0
#define YP_SIZE 8464              // covers y indices [-2048, 6416) (zero padded)
#define WAo     (YP_SIZE)         // WA[i]   = W(i - 16)
#define WA_SIZE 4144
#define WBo     (WAo + WA_SIZE)   // WB[i]   = W(i - 15)   (+1 shifted copy)
#define WB_SIZE 4144
#define LDS_USHORTS (WBo + WB_SIZE)   // 16752 ushorts = 33504 B

using short8 = __attribute__((ext_vector_type(8))) short;
using f32x4  = __attribute__((ext_vector_type(4))) float;
using uint4v = __attribute__((ext_vector_type(4))) unsigned int;

__device__ __forceinline__ unsigned short bf16b(float x) {
    unsigned int u = __float_as_uint(x);
    u += 0x7FFFu + ((u >> 16) & 1u);      // RNE
    return (unsigned short)(u >> 16);
}

__global__ __launch_bounds__(256, 2)
void corr1d_mfma_kernel(const float* __restrict__ X, float* __restrict__ out,
                        float* __restrict__ ws, int use_ws) {
    __shared__ __align__(16) unsigned short lds[LDS_USHORTS];

    const int tid = threadIdx.x;
    const int bid = blockIdx.x;
    const int b = bid & 31;       // same-b blocks share XCD slot (bid%8 == b%8)
    const int f = bid >> 5;

    // ---- zero LDS (padding regions) ----
    unsigned int* l32 = (unsigned int*)lds;
    for (int i = tid; i < LDS_USHORTS / 2; i += 256) l32[i] = 0u;
    __syncthreads();

    // ---- stage y, w (strided column reads, bf16 convert) ----
    const int xbase = b * (T_LEN * 2 * F_CH) + f;
    for (int s = tid; s < T_LEN; s += 256) {
        float yv = X[xbase + s * (2 * F_CH)];
        float wv = X[xbase + s * (2 * F_CH) + F_CH];
        lds[YP + 2048 + s] = bf16b(yv);
        unsigned short wb = bf16b(wv);
        lds[WAo + 16 + s] = wb;
        lds[WBo + 15 + s] = wb;
    }
    __syncthreads();

    // ---- compute ----
    const int lane = tid & 63;
    const int wv   = tid >> 6;
    const int nn   = lane & 15;       // B: column n   / A: row ti
    const int q    = lane >> 4;       // 0..3
    const int ko   = q << 3;          // k-offset (8 per lane group)

    f32x4 acc[16];
#pragma unroll
    for (int h = 0; h < 16; ++h) acc[h] = (f32x4)0.0f;

    short8 cache[16];

    // A-fragment base: W[sigma0 + r], sigma0 = -1 + 32p + 256m + ko - ti
    // odd ti  -> sigma0 even -> WA at sigma0+16
    // even ti -> sigma0 odd  -> WB at sigma0+15   (both even indices)
    const int tiOdd = nn & 1;
    const unsigned short* wbase = tiOdd ? &lds[WAo] : &lds[WBo];
    const int aoff0 = (tiOdd ? 15 : 14) + ko - nn;          // even, >= 0
    const unsigned short* ybase = &lds[YP];
    const int yoff0 = 16 * nn + ko;

    for (int pp = 0; pp < 2; ++pp) {
        const int p = wv * 2 + pp;                          // pass 0..7
        const int yoff = yoff0 + 32 * p;
        const unsigned int* abase =
            (const unsigned int*)(wbase + (aoff0 + 32 * p));

        // preload 16 B fragments (positions 0..15)
#pragma unroll
        for (int s = 0; s < 16; ++s)
            cache[s] = *(const short8*)(ybase + yoff + 256 * s);

#pragma unroll
        for (int M = 0; M < 16; ++M) {
            unsigned int a0 = abase[128 * M + 0];
            unsigned int a1 = abase[128 * M + 1];
            unsigned int a2 = abase[128 * M + 2];
            unsigned int a3 = abase[128 * M + 3];
            uint4v av = {a0, a1, a2, a3};
            short8 af = __builtin_bit_cast(short8, av);
#pragma unroll
            for (int h = 0; h < 16; ++h)
                acc[h] = __builtin_amdgcn_mfma_f32_16x16x32_bf16(
                    af, cache[(h + M) & 15], acc[h], 0, 0, 0);
            // prefetch position M+16 into the slot just freed
            cache[M] = *(const short8*)(ybase + yoff + 256 * (M + 16));
        }

        if (p == 0) {   // extra iteration M = 16 (d = +128)
            unsigned int a0 = abase[2048];
            unsigned int a1 = abase[2049];
            unsigned int a2 = abase[2050];
            unsigned int a3 = abase[2051];
            uint4v av = {a0, a1, a2, a3};
            short8 af = __builtin_bit_cast(short8, av);
#pragma unroll
            for (int h = 0; h < 16; ++h)
                acc[h] = __builtin_amdgcn_mfma_f32_16x16x32_bf16(
                    af, cache[h], acc[h], 0, 0, 0);
        }
    }

    // ---- cross-wave reduction (reuse LDS as 2 x 4096 f32) ----
    __syncthreads();
    float* red = (float*)lds;
    const int tbase = 16 * nn + 4 * q;   // t = 256h + tbase + r

    if (wv >= 2) {
        float* dst = red + (wv - 2) * 4096;
#pragma unroll
        for (int h = 0; h < 16; ++h)
#pragma unroll
            for (int r = 0; r < 4; ++r)
                dst[256 * h + tbase + r] = acc[h][r];
    }
    __syncthreads();
    if (wv < 2) {
        const float* src = red + wv * 4096;
#pragma unroll
        for (int h = 0; h < 16; ++h)
#pragma unroll
            for (int r = 0; r < 4; ++r)
                acc[h][r] += src[256 * h + tbase + r];
    }
    __syncthreads();
    if (wv < 2) {
        float* dst = red + wv * 4096;
#pragma unroll
        for (int h = 0; h < 16; ++h)
#pragma unroll
            for (int r = 0; r < 4; ++r)
                dst[256 * h + tbase + r] = acc[h][r];
    }
    __syncthreads();

    // ---- final sum + store ----
    if (use_ws) {
        // block-private contiguous 16 KB slab: ws[(b*32+f)*4096 + t]
        float* wsb = ws + ((size_t)(b * F_CH + f) << 12);
#pragma unroll
        for (int j = 0; j < 4; ++j) {
            int base = 4 * tid + 1024 * j;
            f32x4 v;
#pragma unroll
            for (int r = 0; r < 4; ++r)
                v[r] = red[base + r] + red[4096 + base + r];
            *(f32x4*)(wsb + base) = v;
        }
    } else {
        const int obase = b * (T_LEN * F_CH) + f;
        for (int j = 0; j < 16; ++j) {
            int t = tid + 256 * j;
            out[obase + t * F_CH] = red[t] + red[4096 + t];
        }
    }
}

// ws(b,f,t) -> out(b,t,f); 32x32 tiles; each output 128-B line has one writer.
__global__ __launch_bounds__(256)
void corr1d_transpose_kernel(const float* __restrict__ ws,
                             float* __restrict__ out) {
    __shared__ float tile[32][33];
    const int blk = blockIdx.x;
    const int b  = blk >> 7;
    const int t0 = (blk & 127) << 5;
    const int a  = threadIdx.x >> 5;   // 0..7
    const int j  = threadIdx.x & 31;

#pragma unroll
    for (int ff = a; ff < 32; ff += 8)
        tile[ff][j] = ws[((size_t)(b * F_CH + ff) << 12) + t0 + j];
    __syncthreads();
#pragma unroll
    for (int jj = a; jj < 32; jj += 8)
        out[b * (T_LEN * F_CH) + (t0 + jj) * F_CH + j] = tile[j][jj];
}

extern "C" void kernel_launch(void* const* d_in, const int* in_sizes, int n_in,
                              void* d_out, int out_size, void* d_ws, size_t ws_size,
                              hipStream_t stream) {
    const float* X = (const float*)d_in[0];
    float* out = (float*)d_out;
    (void)in_sizes; (void)n_in; (void)out_size;

    const size_t need = (size_t)T_LEN * F_CH * 32 * sizeof(float);  // 16 MiB
    const int use_ws = (d_ws != nullptr && ws_size >= need) ? 1 : 0;

    corr1d_mfma_kernel<<<dim3(32 * F_CH), dim3(256), 0, stream>>>(
        X, out, (float*)d_ws, use_ws);
    if (use_ws)
        corr1d_transpose_kernel<<<dim3(32 * 128), dim3(256), 0, stream>>>(
            (const float*)d_ws, out);
}

// Round 3
// 49.381 us; speedup vs baseline: 1.0855x; 1.0855x over previous
//
#include <hip/hip_runtime.h>

// ---------------------------------------------------------------------------
// Depthwise 1-D full correlation, per (batch, filter):
//   out[t] = sum_s y[s] * w[2047 + s - t],   t, s in [0, 4096)
// K0: transpose/convert X[b][s][c] (f32) -> bf16 slabs ws[(b,f)] = [y|w|wshift]
// K1: block-Toeplitz bf16 MFMA (16x16x32), fp32 accumulate; one block per
//     (b,f); coalesced slab staging; XOR-swizzled y region in LDS; writes
//     fp32 out over its own slab (block-private -> no cross-XCD line sharing).
// K2: 32x32 transpose slabs -> out[b][t][f]; one writer per 128-B line.
// ---------------------------------------------------------------------------

#define T_LEN 4096
#define F_CH  32

// K1 LDS layout (ushort units)
#define YP_G   1056                 // y region granules (8 ushorts each)
#define YP_SZ  8448                 // y region: sample s at index 2048+s, swizzled
#define WAo    8448                 // WA[16+i] = w[i]
#define WBo    12592                // WB[15+i] = w[i]
#define LDS_US 16736                // 33472 B

using short8 = __attribute__((ext_vector_type(8))) short;
using f32x4  = __attribute__((ext_vector_type(4))) float;
using uint4v = __attribute__((ext_vector_type(4))) unsigned int;

__device__ __forceinline__ unsigned short bf16b(float x) {
    unsigned int u = __float_as_uint(x);
    u += 0x7FFFu + ((u >> 16) & 1u);      // RNE
    return (unsigned short)(u >> 16);
}

// y-region swizzle: granule g -> g ^ ((g>>3)&7)  (bijective per 8-block)
#define YADDR(e) ((((e) >> 3) ^ (((e) >> 6) & 7)) << 3)

// ---------------------------------------------------------------------------
__global__ __launch_bounds__(256)
void k0_stage(const float* __restrict__ X, unsigned short* __restrict__ ws,
              int has_shift, int slab_us) {
    __shared__ unsigned short tile[64 * 130];
    const int tid = threadIdx.x;
    const int b  = blockIdx.x >> 5;
    const int s0 = (blockIdx.x & 31) << 7;       // 128-row tile

    const float* xb = X + ((size_t)b * T_LEN + s0) * 64;
#pragma unroll
    for (int i = 0; i < 8; ++i) {
        int d4 = 4 * (tid + 256 * i);            // dword idx, 4 per thread
        int row = d4 >> 6, c0 = d4 & 63;
        f32x4 xv = *(const f32x4*)(xb + (size_t)row * 64 + c0);
#pragma unroll
        for (int k = 0; k < 4; ++k)
            tile[(c0 + k) * 130 + row] = bf16b(xv[k]);
    }
    __syncthreads();

    // y & w slabs, dword stores (coalesced per wave)
#pragma unroll
    for (int i = 0; i < 16; ++i) {
        int dw = tid + 256 * i;                  // 0..4095
        int c = dw >> 6, j0 = (dw & 63) * 2;
        unsigned int two = (unsigned int)tile[c * 130 + j0]
                         | ((unsigned int)tile[c * 130 + j0 + 1] << 16);
        unsigned short* slab;
        int off;
        if (c < 32) { slab = ws + (size_t)(b * 32 + c) * slab_us; off = s0 + j0; }
        else { slab = ws + (size_t)(b * 32 + (c - 32)) * slab_us; off = 4096 + s0 + j0; }
        *(unsigned int*)(slab + off) = two;
    }

    if (has_shift) {                             // wshift[i] = w[i+1]
#pragma unroll
        for (int i = 0; i < 16; ++i) {
            int e = tid + 256 * i;               // 0..4095
            int c = e >> 7, j = e & 127;
            int dst = s0 - 1 + j;
            if (dst >= 0)
                ws[(size_t)(b * 32 + c) * slab_us + 8192 + dst] =
                    tile[(c + 32) * 130 + j];
        }
        if (s0 == T_LEN - 128 && tid < 32)
            ws[(size_t)(b * 32 + tid) * slab_us + 8192 + 4095] = 0;
    }
}

// ---------------------------------------------------------------------------
__global__ __launch_bounds__(256, 3)
void corr1d_mfma_kernel(unsigned short* __restrict__ ws,
                        int has_shift, int slab_us) {
    __shared__ __align__(16) unsigned short lds[LDS_US];
    const int tid = threadIdx.x;
    const int b = blockIdx.x & 31;               // same-b blocks share an XCD
    const int f = blockIdx.x >> 5;
    unsigned short* slab = ws + (size_t)(b * 32 + f) * slab_us;

    // ---- zero pad regions ----
    f32x4 z4 = (f32x4)0.0f;
    *(f32x4*)(lds + 8 * tid) = z4;                            // y gran [0,256)
    *(f32x4*)(lds + 8 * (768 + tid)) = z4;                    // y gran [768,1024)
    if (tid < 32) *(f32x4*)(lds + 8 * (1024 + tid)) = z4;     // y gran [1024,1056)
    if (tid < 2)       *(f32x4*)(lds + WAo + 8 * tid) = z4;              // WA [0,16)
    else if (tid < 6)  *(f32x4*)(lds + WAo + 4112 + 8 * (tid - 2)) = z4; // WA [4112,4144)
    else if (tid == 6) {
        *(f32x4*)(lds + WBo) = z4;                                       // WB [0,8)
        for (int i = 8; i < 15; ++i) lds[WBo + i] = 0;
        if (has_shift) lds[WBo + 15] = slab[4096];            // = w[0]
        else           lds[WBo + 4111] = 0;
    } else if (tid >= 8 && tid < 12)
        *(f32x4*)(lds + WBo + 4112 + 8 * (tid - 8)) = z4;                // WB [4112,4144)

    // ---- stage data (coalesced uint4) ----
    const uint4v* sv = (const uint4v*)slab;
#pragma unroll
    for (int r = 0; r < 2; ++r) {
        int c = tid + 256 * r;                   // 0..511
        uint4v vy = sv[c];
        int g = 256 + c;
        *(uint4v*)(lds + ((g ^ ((g >> 3) & 7)) << 3)) = vy;   // swizzled y
        uint4v vw = sv[512 + c];
        *(uint4v*)(lds + WAo + 16 + 8 * c) = vw;
        if (has_shift) {
            uint4v vs = sv[1024 + c];
            *(uint4v*)(lds + WBo + 16 + 8 * c) = vs;
        }
    }
    __syncthreads();
    if (!has_shift) {                            // fallback: build WB in LDS
        for (int i = tid; i < 4096; i += 256)
            lds[WBo + 15 + i] = lds[WAo + 16 + i];
        __syncthreads();
    }

    // ---- compute (verified core) ----
    const int lane = tid & 63;
    const int wv   = tid >> 6;
    const int nn   = lane & 15;
    const int q    = lane >> 4;
    const int ko   = q << 3;

    f32x4 acc[16];
#pragma unroll
    for (int h = 0; h < 16; ++h) acc[h] = (f32x4)0.0f;

    short8 cache[16];

    const int tiOdd = nn & 1;
    const unsigned short* wbase = tiOdd ? &lds[WAo] : &lds[WBo];
    const int aoff0 = (tiOdd ? 15 : 14) + ko - nn;           // even, >= 0
    const unsigned short* ybase = &lds[0];
    const int yoff0 = 16 * nn + ko;

    for (int pp = 0; pp < 2; ++pp) {
        const int p = wv * 2 + pp;                           // pass 0..7
        const int yoff = yoff0 + 32 * p;
        const unsigned int* abase =
            (const unsigned int*)(wbase + (aoff0 + 32 * p));

#pragma unroll
        for (int s = 0; s < 16; ++s)
            cache[s] = *(const short8*)(ybase + YADDR(yoff + 256 * s));

#pragma unroll
        for (int M = 0; M < 16; ++M) {
            unsigned int a0 = abase[128 * M + 0];
            unsigned int a1 = abase[128 * M + 1];
            unsigned int a2 = abase[128 * M + 2];
            unsigned int a3 = abase[128 * M + 3];
            uint4v av = {a0, a1, a2, a3};
            short8 af = __builtin_bit_cast(short8, av);
#pragma unroll
            for (int h = 0; h < 16; ++h)
                acc[h] = __builtin_amdgcn_mfma_f32_16x16x32_bf16(
                    af, cache[(h + M) & 15], acc[h], 0, 0, 0);
            cache[M] = *(const short8*)(ybase + YADDR(yoff + 256 * (M + 16)));
        }

        if (p == 0) {                                        // extra M=16
            unsigned int a0 = abase[2048];
            unsigned int a1 = abase[2049];
            unsigned int a2 = abase[2050];
            unsigned int a3 = abase[2051];
            uint4v av = {a0, a1, a2, a3};
            short8 af = __builtin_bit_cast(short8, av);
#pragma unroll
            for (int h = 0; h < 16; ++h)
                acc[h] = __builtin_amdgcn_mfma_f32_16x16x32_bf16(
                    af, cache[h], acc[h], 0, 0, 0);
        }
    }

    // ---- cross-wave reduction (LDS as 2 x 4096 f32) ----
    __syncthreads();
    float* red = (float*)lds;
    const int tbase = 16 * nn + 4 * q;

    if (wv >= 2) {
        float* dst = red + (wv - 2) * 4096;
#pragma unroll
        for (int h = 0; h < 16; ++h)
#pragma unroll
            for (int r = 0; r < 4; ++r)
                dst[256 * h + tbase + r] = acc[h][r];
    }
    __syncthreads();
    if (wv < 2) {
        const float* src = red + wv * 4096;
#pragma unroll
        for (int h = 0; h < 16; ++h)
#pragma unroll
            for (int r = 0; r < 4; ++r)
                acc[h][r] += src[256 * h + tbase + r];
    }
    __syncthreads();
    if (wv < 2) {
        float* dst = red + wv * 4096;
#pragma unroll
        for (int h = 0; h < 16; ++h)
#pragma unroll
            for (int r = 0; r < 4; ++r)
                dst[256 * h + tbase + r] = acc[h][r];
    }
    __syncthreads();

    // ---- final sum + store to own slab (block-private) ----
    float* slabf = (float*)slab;
#pragma unroll
    for (int j = 0; j < 4; ++j) {
        int base = 4 * tid + 1024 * j;
        f32x4 v;
#pragma unroll
        for (int r = 0; r < 4; ++r)
            v[r] = red[base + r] + red[4096 + base + r];
        *(f32x4*)(slabf + base) = v;
    }
}

// ---------------------------------------------------------------------------
__global__ __launch_bounds__(256)
void k2_out(const unsigned short* __restrict__ ws, float* __restrict__ out,
            int slab_us) {
    __shared__ float tile[32][33];
    const int blk = blockIdx.x;
    const int b  = blk >> 7;
    const int t0 = (blk & 127) << 5;
    const int a  = threadIdx.x >> 5;
    const int j  = threadIdx.x & 31;

#pragma unroll
    for (int ff = a; ff < 32; ff += 8)
        tile[ff][j] =
            ((const float*)(ws + (size_t)(b * 32 + ff) * slab_us))[t0 + j];
    __syncthreads();
#pragma unroll
    for (int jj = a; jj < 32; jj += 8)
        out[b * (T_LEN * F_CH) + (t0 + jj) * F_CH + j] = tile[j][jj];
}

// ---------------------------------------------------------------------------
extern "C" void kernel_launch(void* const* d_in, const int* in_sizes, int n_in,
                              void* d_out, int out_size, void* d_ws, size_t ws_size,
                              hipStream_t stream) {
    const float* X = (const float*)d_in[0];
    float* out = (float*)d_out;
    (void)in_sizes; (void)n_in; (void)out_size;

    const size_t need3 = (size_t)1024 * 12288 * 2;   // 25.2 MB (with wshift)
    int has_shift, slab_us;
    if (ws_size >= need3) { has_shift = 1; slab_us = 12288; }
    else                  { has_shift = 0; slab_us = 8192;  }   // >=16 MiB verified
    unsigned short* ws = (unsigned short*)d_ws;

    k0_stage<<<dim3(1024), dim3(256), 0, stream>>>(X, ws, has_shift, slab_us);
    corr1d_mfma_kernel<<<dim3(1024), dim3(256), 0, stream>>>(ws, has_shift, slab_us);
    k2_out<<<dim3(4096), dim3(256), 0, stream>>>(ws, out, slab_us);
}